// Round 3
// baseline (186.582 us; speedup 1.0000x reference)
//
#include <hip/hip_runtime.h>

// Problem constants (from setup_inputs)
constexpr int NROIS = 2000;
constexpr int Hh = 100, Ww = 100, Cc = 256;
constexpr int CH = 7, CW = 7;
constexpr int C4 = Cc / 4;            // 64 float4 per pixel = one wave per pixel
constexpr int PIX = NROIS * CH * CW;  // 98000 output pixels
constexpr int PPW = 4;                // pixels per wave

typedef float v4f __attribute__((ext_vector_type(4)));  // native vector: OK for nontemporal builtins

__global__ __launch_bounds__(256) void roi_crop_resize_kernel(
    const float* __restrict__ fm,    // [B, H, W, C]
    const float* __restrict__ rois,  // [N, 5] = (bidx, x1, y1, x2, y2) pixel units
    float* __restrict__ out)         // [N, 7, 7, C]
{
    const int lane = threadIdx.x & 63;          // channel group c4
    const int wave = threadIdx.x >> 6;
    const int pbase = (blockIdx.x * 4 + wave) * PPW;
    const v4f* __restrict__ fm4 = (const v4f*)fm;
    v4f* __restrict__ out4 = (v4f*)out;

#pragma unroll
    for (int k = 0; k < PPW; ++k) {
        int p = pbase + k;
        int n = p / (CH * CW);                  // magic-div by 49
        int ij = p - n * (CH * CW);
        int i = ij / CW;                        // magic-div by 7
        int j = ij - i * CW;

        const float* r = rois + (size_t)n * 5;
        int   b  = (int)r[0];
        float x1 = r[1] / (float)Ww;
        float y1 = r[2] / (float)Hh;
        float x2 = r[3] / (float)Ww;
        float y2 = r[4] / (float)Hh;

        float in_y = y1 * (float)(Hh - 1)
                   + (float)i * ((y2 - y1) * (float)(Hh - 1) / (float)(CH - 1));
        float in_x = x1 * (float)(Ww - 1)
                   + (float)j * ((x2 - x1) * (float)(Ww - 1) / (float)(CW - 1));

        // Branchless: always load with clamped indices, mask the result.
        bool valid = (in_y >= 0.f) && (in_y <= (float)(Hh - 1)) &&
                     (in_x >= 0.f) && (in_x <= (float)(Ww - 1));
        float m = valid ? 1.f : 0.f;

        float fy = floorf(in_y), fx = floorf(in_x);
        float ly = in_y - fy,    lx = in_x - fx;
        int ty = min(Hh - 1, max(0, (int)fy));
        int by = min(Hh - 1, max(0, (int)ceilf(in_y)));
        int tx = min(Ww - 1, max(0, (int)fx));
        int bx = min(Ww - 1, max(0, (int)ceilf(in_x)));

        size_t base = (size_t)b * Hh * Ww;
        size_t rT = base + (size_t)ty * Ww;
        size_t rB = base + (size_t)by * Ww;

        v4f tl = fm4[(rT + tx) * C4 + lane];
        v4f tr = fm4[(rT + bx) * C4 + lane];
        v4f bl = fm4[(rB + tx) * C4 + lane];
        v4f br = fm4[(rB + bx) * C4 + lane];

        v4f top = tl + (tr - tl) * lx;
        v4f bot = bl + (br - bl) * lx;
        v4f o   = (top + (bot - top) * ly) * m;

        __builtin_nontemporal_store(o, out4 + (size_t)p * C4 + lane);
    }
}

extern "C" void kernel_launch(void* const* d_in, const int* in_sizes, int n_in,
                              void* d_out, int out_size, void* d_ws, size_t ws_size,
                              hipStream_t stream) {
    const float* fm   = (const float*)d_in[0];   // [8,100,100,256] fp32
    const float* rois = (const float*)d_in[1];   // [2000,5] fp32
    float* out = (float*)d_out;                  // [2000,7,7,256] fp32

    constexpr int threads = 256;
    constexpr int blocks  = PIX / (4 * PPW);     // 98000 / 16 = 6125 (exact)
    roi_crop_resize_kernel<<<blocks, threads, 0, stream>>>(fm, rois, out);
}